// Round 4
// baseline (33246.811 us; speedup 1.0000x reference)
//
#include <hip/hip_runtime.h>

#define TINN 512
#define FF 64
#define HHD 512
#define TOUTN 64

using v8h = __attribute__((ext_vector_type(8))) _Float16;
using v4h = __attribute__((ext_vector_type(4))) _Float16;
using v4f = __attribute__((ext_vector_type(4))) float;

// ---------------- LDS layout (bytes) ----------------
#define WOFF 0
#define SB_ENC0 1168   // K=576  -> 576*2+16
#define SB_ENC1 2064   // K=1024 -> 1024*2+16
#define SB_DEC0 1040   // K=512  -> 512*2+16
#define AOFF 132096    // A chunk double buffer: 2 x (64 rows x 144B)
#define ABUFSZ 9216
#define GBUF_OFF AOFF  // epilogue gate buffer 64x65 f32 = 16640B, aliases A bufs
#define BIAS_OFF 150528
#define WIH0_OFF 150784
#define PREV_OFF 151040
#define PART_OFF 151296
#define PROJW_OFF 152320
#define PROJB_OFF 154368
#define SMEM_TOTAL 154624

// ---------------- workspace layout ----------------
// Barrier: 4 groups x 64 slots x 64B = 16 KB (memset each launch).
// Slot-per-block flag barrier: arrival = atomic store of generation to own
// slot (no RMW contention); wait = 64 lanes poll 64 distinct slots in one
// vector load per round (exec-mask loop retires lanes as they observe it).
#define WS_BAR 0
#define WS_HOFF 16384  // h0[0], h0[1], h1[0], h1[1] : each 256*512*2 = 262144 B
#define HBYTES (256 * HHD * 2)

static __device__ __forceinline__ float sigm(float x) { return 1.0f / (1.0f + __expf(-x)); }
static __device__ __forceinline__ float tanh_f(float x) { return 1.0f - 2.0f / (1.0f + __expf(2.0f * x)); }

// Group-local (64-block) barrier, contention-free.
// slots = this group's 64-slot array; r = block's rank in group; target =
// monotonically increasing generation (same sequence in every block).
static __device__ void groupBarrier(unsigned* slots, int r, unsigned target) {
  __threadfence();
  __syncthreads();
  if (threadIdx.x < 64) {
    if (threadIdx.x == 0) {
      __hip_atomic_store(&slots[(size_t)r * 16], target,
                         __ATOMIC_RELEASE, __HIP_MEMORY_SCOPE_AGENT);
    }
    while (__hip_atomic_load(&slots[(size_t)threadIdx.x * 16],
                             __ATOMIC_ACQUIRE, __HIP_MEMORY_SCOPE_AGENT) < target) {
      __builtin_amdgcn_s_sleep(1);
    }
  }
  __syncthreads();
}

// Weight slice (64 gate-cols x K) fp32->fp16 into LDS.
// col c -> gate (c>>4), n = (c>>4)*512 + hc0 + (c&15). K-order: [W1 (K1) | W2].
static __device__ __attribute__((noinline)) void loadWeights(
    int tid, int hc0, const float* W1, int ld1, int K1,
    const float* W2, int K, int SB) {
  extern __shared__ char smem[];
  int c = tid >> 2, sub = tid & 3;
  int n = (c >> 4) * HHD + hc0 + (c & 15);
  int Kq = K >> 2;
  _Float16* dst = (_Float16*)(smem + WOFF + (size_t)c * SB);
  for (int k = sub * Kq; k < (sub + 1) * Kq; ++k) {
    float v;
    if (k < K1) v = W1[(size_t)n * ld1 + k];
    else        v = W2[(size_t)n * HHD + (k - K1)];
    dst[k] = (_Float16)v;
  }
}

static __device__ __forceinline__ void loadChunkRegs(
    int ci, const float* xstep, const _Float16* src1, const _Float16* src2,
    int m0, int tid, v8h* r0, v8h* r1) {
  int row = tid >> 2, s4 = tid & 3;
  if (xstep != nullptr && ci == 0) {
    const float* xp = xstep + (size_t)(m0 + row) * (TINN * FF) + s4 * 16;
    v4f f0 = *(const v4f*)(xp);
    v4f f1 = *(const v4f*)(xp + 4);
    v4f f2 = *(const v4f*)(xp + 8);
    v4f f3 = *(const v4f*)(xp + 12);
    v8h a, b;
#pragma unroll
    for (int e = 0; e < 4; ++e) {
      a[e] = (_Float16)f0[e]; a[4 + e] = (_Float16)f1[e];
      b[e] = (_Float16)f2[e]; b[4 + e] = (_Float16)f3[e];
    }
    *r0 = a; *r1 = b;
  } else {
    int cj = ci - (xstep != nullptr ? 1 : 0);
    const _Float16* s = (cj < 8) ? src1 : src2;
    int col = ((cj < 8) ? cj : (cj - 8)) * 64;
    const _Float16* hp = s + (size_t)(m0 + row) * HHD + col + s4 * 16;
    *r0 = *(const v8h*)(hp);
    *r1 = *(const v8h*)(hp + 8);
  }
}

// One LSTM cell step for this block's (m0 batch rows, hc0 h-cols) 64x16 tile.
static __device__ __attribute__((noinline)) void gemmStep(
    int tid, int m0, int hc0, const float* xstep,
    const _Float16* src1, const _Float16* src2,
    int NC, int SB, int rank1, _Float16* hout, float* creg) {
  extern __shared__ char smem[];
  int lane = tid & 63, wave = tid >> 6;
  int wm = wave >> 1, wn = wave & 1;
  int l15 = lane & 15, quad = lane >> 4;
  int row = tid >> 2, s4 = tid & 3;

  v4f acc00 = {0.f, 0.f, 0.f, 0.f};
  v4f acc01 = {0.f, 0.f, 0.f, 0.f};
  v4f acc10 = {0.f, 0.f, 0.f, 0.f};
  v4f acc11 = {0.f, 0.f, 0.f, 0.f};

  v8h r0, r1;
  loadChunkRegs(0, xstep, src1, src2, m0, tid, &r0, &r1);
  {
    char* p = smem + AOFF + row * 144 + s4 * 32;
    *(v8h*)(p) = r0;
    *(v8h*)(p + 16) = r1;
  }

  for (int ci = 0; ci < NC; ++ci) {
    bool more = (ci + 1 < NC);
    if (more) loadChunkRegs(ci + 1, xstep, src1, src2, m0, tid, &r0, &r1);
    __syncthreads();  // chunk ci staged; prior reads of other buffer done
    char* ab = smem + AOFF + (ci & 1) * ABUFSZ;
    char* wb = smem + WOFF;
    int kc0 = ci * 64;
#pragma unroll
    for (int ks = 0; ks < 2; ++ks) {
      v8h a0 = *(const v8h*)(ab + (wm * 32 + l15) * 144 + ks * 64 + quad * 16);
      v8h a1 = *(const v8h*)(ab + (wm * 32 + 16 + l15) * 144 + ks * 64 + quad * 16);
      v8h b0 = *(const v8h*)(wb + (size_t)(wn * 32 + l15) * SB + kc0 * 2 + ks * 64 + quad * 16);
      v8h b1 = *(const v8h*)(wb + (size_t)(wn * 32 + 16 + l15) * SB + kc0 * 2 + ks * 64 + quad * 16);
      acc00 = __builtin_amdgcn_mfma_f32_16x16x32_f16(a0, b0, acc00, 0, 0, 0);
      acc01 = __builtin_amdgcn_mfma_f32_16x16x32_f16(a0, b1, acc01, 0, 0, 0);
      acc10 = __builtin_amdgcn_mfma_f32_16x16x32_f16(a1, b0, acc10, 0, 0, 0);
      acc11 = __builtin_amdgcn_mfma_f32_16x16x32_f16(a1, b1, acc11, 0, 0, 0);
    }
    if (more) {
      char* p = smem + AOFF + ((ci + 1) & 1) * ABUFSZ + row * 144 + s4 * 32;
      *(v8h*)(p) = r0;
      *(v8h*)(p + 16) = r1;
    }
  }
  __syncthreads();  // all frag reads done; A bufs free -> reuse as gbuf

  float* gb = (float*)(smem + GBUF_OFF);
#pragma unroll
  for (int r = 0; r < 4; ++r) {
    gb[(wm * 32 + quad * 4 + r) * 65 + wn * 32 + l15] = acc00[r];
    gb[(wm * 32 + quad * 4 + r) * 65 + wn * 32 + 16 + l15] = acc01[r];
    gb[(wm * 32 + 16 + quad * 4 + r) * 65 + wn * 32 + l15] = acc10[r];
    gb[(wm * 32 + 16 + quad * 4 + r) * 65 + wn * 32 + 16 + l15] = acc11[r];
  }
  __syncthreads();

  float* bias = (float*)(smem + BIAS_OFF);
  float* wih0 = (float*)(smem + WIH0_OFF);
  float* prevl = (float*)(smem + PREV_OFF);
  int m = tid >> 2, jb = (tid & 3) * 4;
  float pv = rank1 ? prevl[m] : 0.0f;
  v4h hh;
#pragma unroll
  for (int i = 0; i < 4; ++i) {
    int j = jb + i;
    float gi = gb[m * 65 + j] + bias[j];
    float gf = gb[m * 65 + 16 + j] + bias[16 + j];
    float gg = gb[m * 65 + 32 + j] + bias[32 + j];
    float go = gb[m * 65 + 48 + j] + bias[48 + j];
    if (rank1) {
      gi += pv * wih0[j]; gf += pv * wih0[16 + j];
      gg += pv * wih0[32 + j]; go += pv * wih0[48 + j];
    }
    float c = sigm(gf) * creg[i] + sigm(gi) * tanh_f(gg);
    float h = sigm(go) * tanh_f(c);
    creg[i] = c;
    hh[i] = (_Float16)h;
  }
  *(v4h*)(hout + (size_t)(m0 + m) * HHD + hc0 + jb) = hh;
  // caller's groupBarrier provides the sync before gbuf/A region is reused
}

__global__ void __launch_bounds__(256, 1)
seq2seq_kernel(const float* x,
               const float* e0wi, const float* e0wh, const float* e0bi, const float* e0bh,
               const float* e1wi, const float* e1wh, const float* e1bi, const float* e1bh,
               const float* d0wi, const float* d0wh, const float* d0bi, const float* d0bh,
               const float* d1wi, const float* d1wh, const float* d1bi, const float* d1bh,
               const float* pw, const float* pb,
               float* out, char* ws) {
  extern __shared__ char smem[];
  int tid = threadIdx.x, bid = blockIdx.x;
  int group = bid >> 6;       // 4 groups x 64 blocks; group owns batch rows [64g, 64g+64)
  int r = bid & 63;
  bool isL1 = (r >= 32);
  int hcTile = r & 31;
  int hc0 = hcTile * 16;
  int m0 = group * 64;
  unsigned* slots = (unsigned*)(ws + WS_BAR) + (size_t)group * 1024;  // 64 slots x 64B
  unsigned barGen = 0;

  _Float16* h0b[2]; _Float16* h1b[2];
  h0b[0] = (_Float16*)(ws + WS_HOFF);
  h0b[1] = (_Float16*)(ws + WS_HOFF + HBYTES);
  h1b[0] = (_Float16*)(ws + WS_HOFF + 2 * HBYTES);
  h1b[1] = (_Float16*)(ws + WS_HOFF + 3 * HBYTES);

  float creg[4];
  creg[0] = 0.f; creg[1] = 0.f; creg[2] = 0.f; creg[3] = 0.f;

  // zero this group's slice of all four h buffers (group-aligned so the
  // group-local barrier is a sufficient ordering guarantee)
  {
    int q = r >> 4;     // which buffer
    int rb = r & 15;    // 4-row block within group's 64 rows
    char* zp = ws + WS_HOFF + (size_t)q * HBYTES +
               ((size_t)(m0 + rb * 4) * HHD) * 2 + (size_t)tid * 16;
    v4f z = {0.f, 0.f, 0.f, 0.f};
    *(v4f*)zp = z;
  }

  // encoder-role weights + biases into LDS
  if (!isL1) {
    loadWeights(tid, hc0, e0wi, 64, 64, e0wh, 576, SB_ENC0);
    if (tid < 64) {
      int n = (tid >> 4) * HHD + hc0 + (tid & 15);
      ((float*)(smem + BIAS_OFF))[tid] = e0bi[n] + e0bh[n];
    }
  } else {
    loadWeights(tid, hc0, e1wi, 512, 512, e1wh, 1024, SB_ENC1);
    if (tid < 64) {
      int n = (tid >> 4) * HHD + hc0 + (tid & 15);
      ((float*)(smem + BIAS_OFF))[tid] = e1bi[n] + e1bh[n];
    }
  }
  barGen++; groupBarrier(slots, r, barGen);

  // -------- encoder: phase p runs enc0 step p and enc1 step p-1 --------
  for (int p = 0; p <= TINN; ++p) {
    if (!isL1) {
      if (p < TINN)
        gemmStep(tid, m0, hc0, x + (size_t)p * FF, h0b[(p & 1) ^ 1], nullptr,
                 9, SB_ENC0, 0, h0b[p & 1], creg);
    } else {
      if (p >= 1) {
        int s = p - 1;
        gemmStep(tid, m0, hc0, nullptr, h0b[s & 1], h1b[(s & 1) ^ 1],
                 16, SB_ENC1, 0, h1b[s & 1], creg);
      }
    }
    barGen++; groupBarrier(slots, r, barGen);
  }

  // -------- switch to decoder-role weights (c state stays in creg) --------
  if (!isL1) {
    loadWeights(tid, hc0, d0wh, 512, 512, nullptr, 512, SB_DEC0);
    if (tid < 64) {
      int n = (tid >> 4) * HHD + hc0 + (tid & 15);
      ((float*)(smem + BIAS_OFF))[tid] = d0bi[n] + d0bh[n];
      ((float*)(smem + WIH0_OFF))[tid] = d0wi[n];
    }
    for (int k = tid; k < 512; k += 256) ((float*)(smem + PROJW_OFF))[k] = pw[k];
    if (tid == 0) ((float*)(smem + PROJB_OFF))[0] = pb[0];
  } else {
    loadWeights(tid, hc0, d1wi, 512, 512, d1wh, 1024, SB_ENC1);
    if (tid < 64) {
      int n = (tid >> 4) * HHD + hc0 + (tid & 15);
      ((float*)(smem + BIAS_OFF))[tid] = d1bi[n] + d1bh[n];
    }
  }
  __syncthreads();
  barGen++; groupBarrier(slots, r, barGen);

  // -------- decoder: 2 phases per step (prev->h0 then h0->h1) --------
  for (int t = 0; t <= TOUTN; ++t) {
    if (!isL1) {
      float* prevl = (float*)(smem + PREV_OFF);
      if (t == 0) {
        if (tid < 64)
          prevl[tid] = x[(size_t)(m0 + tid) * (TINN * FF) + 511 * 64 + 63];
      } else {
        // prev(t) = h1(t-1) . projW + proj_b  (fp32 VALU, 4 threads per row)
        float* part = (float*)(smem + PART_OFF);
        float* pjw = (float*)(smem + PROJW_OFF);
        const _Float16* hrow = h1b[(t - 1) & 1] +
                               (size_t)(m0 + (tid >> 2)) * HHD + (tid & 3) * 128;
        float s = 0.f;
        for (int k8 = 0; k8 < 16; ++k8) {
          v8h hv = *(const v8h*)(hrow + k8 * 8);
          const float* w = pjw + (tid & 3) * 128 + k8 * 8;
#pragma unroll
          for (int e = 0; e < 8; ++e) s += (float)hv[e] * w[e];
        }
        part[tid] = s;
        __syncthreads();
        if (tid < 64) {
          float p4 = part[tid * 4] + part[tid * 4 + 1] + part[tid * 4 + 2] +
                     part[tid * 4 + 3] + ((float*)(smem + PROJB_OFF))[0];
          prevl[tid] = p4;
          if (hcTile == 0) out[(size_t)(m0 + tid) * TOUTN + (t - 1)] = p4;
        }
      }
      __syncthreads();
      if (t < TOUTN)
        gemmStep(tid, m0, hc0, nullptr, h0b[(t & 1) ^ 1], nullptr,
                 8, SB_DEC0, 1, h0b[t & 1], creg);
    }
    barGen++; groupBarrier(slots, r, barGen);
    if (isL1 && t < TOUTN)
      gemmStep(tid, m0, hc0, nullptr, h0b[t & 1], h1b[(t & 1) ^ 1],
               16, SB_ENC1, 0, h1b[t & 1], creg);
    barGen++; groupBarrier(slots, r, barGen);
  }
}

extern "C" void kernel_launch(void* const* d_in, const int* in_sizes, int n_in,
                              void* d_out, int out_size, void* d_ws, size_t ws_size,
                              hipStream_t stream) {
  const float* x = (const float*)d_in[0];
  // d_in[1] = y (only used for output shape in the reference)
  const float* e0wi = (const float*)d_in[2];
  const float* e0wh = (const float*)d_in[3];
  const float* e0bi = (const float*)d_in[4];
  const float* e0bh = (const float*)d_in[5];
  const float* e1wi = (const float*)d_in[6];
  const float* e1wh = (const float*)d_in[7];
  const float* e1bi = (const float*)d_in[8];
  const float* e1bh = (const float*)d_in[9];
  const float* d0wi = (const float*)d_in[10];
  const float* d0wh = (const float*)d_in[11];
  const float* d0bi = (const float*)d_in[12];
  const float* d0bh = (const float*)d_in[13];
  const float* d1wi = (const float*)d_in[14];
  const float* d1wh = (const float*)d_in[15];
  const float* d1bi = (const float*)d_in[16];
  const float* d1bh = (const float*)d_in[17];
  const float* pw = (const float*)d_in[18];
  const float* pb = (const float*)d_in[19];

  (void)hipFuncSetAttribute((const void*)seq2seq_kernel,
                            hipFuncAttributeMaxDynamicSharedMemorySize, SMEM_TOTAL);
  (void)hipMemsetAsync(d_ws, 0, 16384, stream);  // barrier slots (4 groups x 64)
  seq2seq_kernel<<<dim3(256), dim3(256), SMEM_TOTAL, stream>>>(
      x, e0wi, e0wh, e0bi, e0bh, e1wi, e1wh, e1bi, e1bh,
      d0wi, d0wh, d0bi, d0bh, d1wi, d1wh, d1bi, d1bh,
      pw, pb, (float*)d_out, (char*)d_ws);
}

// Round 5
// 11260.229 us; speedup vs baseline: 2.9526x; 2.9526x over previous
//
#include <hip/hip_runtime.h>

#define TINN 512
#define FF 64
#define HHD 512
#define TOUTN 64

using v8h = __attribute__((ext_vector_type(8))) _Float16;
using v4h = __attribute__((ext_vector_type(4))) _Float16;
using v4f = __attribute__((ext_vector_type(4))) float;
using u64 = unsigned long long;

#define AGT __HIP_MEMORY_SCOPE_AGENT

// ---------------- LDS layout (bytes) ----------------
#define WOFF 0
#define SB_ENC0 1168   // K=576  -> 576*2+16
#define SB_ENC1 2064   // K=1024 -> 1024*2+16
#define SB_DEC0 1040   // K=512  -> 512*2+16
#define GBUF_OFF 132096  // 64 x 65 f32 = 16640
#define BIAS_OFF 148736
#define WIH0_OFF 148992
#define PREV_OFF 149248
#define PART_OFF 149504  // 1024
#define PROJW_OFF 150528 // 2048
#define PROJB_OFF 152576
#define SMEM_TOTAL 152832

// ---------------- workspace layout ----------------
#define WS_BAR 0       // 4 groups x 64 slots x 64B = 16 KB (memset each launch)
#define WS_HOFF 16384  // h0[0], h0[1], h1[0], h1[1] : each 256*512*2 = 262144 B
#define HBYTES (256 * HHD * 2)

static __device__ __forceinline__ float sigm(float x) { return 1.0f / (1.0f + __expf(-x)); }
static __device__ __forceinline__ float tanh_f(float x) { return 1.0f - 2.0f / (1.0f + __expf(2.0f * x)); }

// Cross-block data movement: relaxed agent-scope atomics. These lower to
// cache-bypassing (sc0/sc1) accesses serviced at the LLC coherence point —
// NO buffer_wbl2 / buffer_inv fence instructions are ever emitted, so the
// read-only working set (x, weights) stays L2-cached across phases.
static __device__ __forceinline__ v8h aload16(const _Float16* p) {
  union { u64 u[2]; v8h h; } c;
  const u64* q = (const u64*)p;
  c.u[0] = __hip_atomic_load(q, __ATOMIC_RELAXED, AGT);
  c.u[1] = __hip_atomic_load(q + 1, __ATOMIC_RELAXED, AGT);
  return c.h;
}
static __device__ __forceinline__ void astore8(_Float16* p, v4h v) {
  union { u64 u; v4h h; } c;
  c.h = v;
  __hip_atomic_store((u64*)p, c.u, __ATOMIC_RELAXED, AGT);
}
static __device__ __forceinline__ void astore8z(void* p) {
  __hip_atomic_store((u64*)p, 0ull, __ATOMIC_RELAXED, AGT);
}

// Group-local (64-block) barrier, contention-free AND fence-free.
// Each wave drains its own vmem (s_waitcnt 0) before s_barrier, so all h
// atomic stores are LLC-visible before block 0's lane stores the flag.
static __device__ void groupBarrier(unsigned* slots, int r, unsigned target) {
  __builtin_amdgcn_s_waitcnt(0);
  __syncthreads();
  if (threadIdx.x == 0)
    __hip_atomic_store(&slots[(size_t)r * 16], target, __ATOMIC_RELAXED, AGT);
  if (threadIdx.x < 64) {
    while (__hip_atomic_load(&slots[(size_t)threadIdx.x * 16],
                             __ATOMIC_RELAXED, AGT) < target)
      __builtin_amdgcn_s_sleep(1);
  }
  __syncthreads();
}

// Weight slice (64 gate-cols x K) fp32->fp16 into LDS.
// col c -> gate (c>>4), n = (c>>4)*512 + hc0 + (c&15). K-order: [W1 (K1) | W2].
static __device__ __attribute__((noinline)) void loadWeights(
    int tid, int hc0, const float* W1, int ld1, int K1,
    const float* W2, int K, int SB) {
  extern __shared__ char smem[];
  int c = tid >> 2, sub = tid & 3;
  int n = (c >> 4) * HHD + hc0 + (c & 15);
  int Kq = K >> 2;
  _Float16* dst = (_Float16*)(smem + WOFF + (size_t)c * SB);
  for (int k = sub * Kq; k < (sub + 1) * Kq; ++k) {
    float v;
    if (k < K1) v = W1[(size_t)n * ld1 + k];
    else        v = W2[(size_t)n * HHD + (k - K1)];
    dst[k] = (_Float16)v;
  }
}

// One LSTM cell step for this block's (m0 batch rows, hc0 h-cols) 64x16 tile.
// A-fragments load DIRECTLY global->registers (no LDS staging, no K-loop
// syncthreads -> no vmcnt-drain stalls); B (weights) from LDS; fp32 acc.
template <int NC>
static __device__ __attribute__((noinline)) void gemmStep(
    int tid, int m0, int hc0, const float* xstep,
    const _Float16* src1, const _Float16* src2,
    int SB, int rank1, _Float16* hout, float* creg) {
  extern __shared__ char smem[];
  int lane = tid & 63, wave = tid >> 6;
  int wm = wave >> 1, wn = wave & 1;
  int l15 = lane & 15, quad = lane >> 4;

  v4f zero4 = {0.f, 0.f, 0.f, 0.f};
  v4f acc00 = zero4, acc01 = zero4, acc10 = zero4, acc11 = zero4;

  int ra0 = m0 + wm * 32 + l15;   // A row for ms=0
  int ra1 = ra0 + 16;             // A row for ms=1
  const char* wb = smem + WOFF;

#pragma unroll
  for (int ci = 0; ci < NC; ++ci) {
    v8h a0k0, a0k1, a1k0, a1k1;
    if (xstep != nullptr && ci == 0) {
      // chunk 0 of encoder layer0: fp32 x columns 0..63
      const float* xr0 = xstep + (size_t)ra0 * (TINN * FF);
      const float* xr1 = xstep + (size_t)ra1 * (TINN * FF);
#pragma unroll
      for (int ks = 0; ks < 2; ++ks) {
        const float* p0 = xr0 + ks * 32 + quad * 8;
        const float* p1 = xr1 + ks * 32 + quad * 8;
        v4f f00 = *(const v4f*)p0, f01 = *(const v4f*)(p0 + 4);
        v4f f10 = *(const v4f*)p1, f11 = *(const v4f*)(p1 + 4);
        v8h a0, a1;
#pragma unroll
        for (int e = 0; e < 4; ++e) {
          a0[e] = (_Float16)f00[e]; a0[4 + e] = (_Float16)f01[e];
          a1[e] = (_Float16)f10[e]; a1[4 + e] = (_Float16)f11[e];
        }
        if (ks == 0) { a0k0 = a0; a1k0 = a1; } else { a0k1 = a0; a1k1 = a1; }
      }
    } else {
      int cj = (xstep != nullptr) ? (ci - 1) : ci;
      const _Float16* s;
      int off;
      if (src2 == nullptr || cj < 8) { s = src1; off = cj; }
      else                           { s = src2; off = cj - 8; }
      const _Float16* pr0 = s + (size_t)ra0 * HHD + off * 64 + quad * 8;
      const _Float16* pr1 = s + (size_t)ra1 * HHD + off * 64 + quad * 8;
      a0k0 = aload16(pr0);
      a0k1 = aload16(pr0 + 32);
      a1k0 = aload16(pr1);
      a1k1 = aload16(pr1 + 32);
    }
    const char* bbase = wb + ci * 128 + quad * 16;
#pragma unroll
    for (int ks = 0; ks < 2; ++ks) {
      v8h b0 = *(const v8h*)(bbase + (size_t)(wn * 32 + l15) * SB + ks * 64);
      v8h b1 = *(const v8h*)(bbase + (size_t)(wn * 32 + 16 + l15) * SB + ks * 64);
      v8h a0 = ks ? a0k1 : a0k0;
      v8h a1 = ks ? a1k1 : a1k0;
      acc00 = __builtin_amdgcn_mfma_f32_16x16x32_f16(a0, b0, acc00, 0, 0, 0);
      acc01 = __builtin_amdgcn_mfma_f32_16x16x32_f16(a0, b1, acc01, 0, 0, 0);
      acc10 = __builtin_amdgcn_mfma_f32_16x16x32_f16(a1, b0, acc10, 0, 0, 0);
      acc11 = __builtin_amdgcn_mfma_f32_16x16x32_f16(a1, b1, acc11, 0, 0, 0);
    }
  }

  // gates -> LDS (gbuf dedicated region; prior step's reads were fenced by
  // the caller's groupBarrier)
  float* gb = (float*)(smem + GBUF_OFF);
#pragma unroll
  for (int r = 0; r < 4; ++r) {
    gb[(wm * 32 + quad * 4 + r) * 65 + wn * 32 + l15] = acc00[r];
    gb[(wm * 32 + quad * 4 + r) * 65 + wn * 32 + 16 + l15] = acc01[r];
    gb[(wm * 32 + 16 + quad * 4 + r) * 65 + wn * 32 + l15] = acc10[r];
    gb[(wm * 32 + 16 + quad * 4 + r) * 65 + wn * 32 + 16 + l15] = acc11[r];
  }
  __syncthreads();

  float* bias = (float*)(smem + BIAS_OFF);
  float* wih0 = (float*)(smem + WIH0_OFF);
  float* prevl = (float*)(smem + PREV_OFF);
  int m = tid >> 2, jb = (tid & 3) * 4;
  float pv = rank1 ? prevl[m] : 0.0f;
  v4h hh;
#pragma unroll
  for (int i = 0; i < 4; ++i) {
    int j = jb + i;
    float gi = gb[m * 65 + j] + bias[j];
    float gf = gb[m * 65 + 16 + j] + bias[16 + j];
    float gg = gb[m * 65 + 32 + j] + bias[32 + j];
    float go = gb[m * 65 + 48 + j] + bias[48 + j];
    if (rank1) {
      gi += pv * wih0[j]; gf += pv * wih0[16 + j];
      gg += pv * wih0[32 + j]; go += pv * wih0[48 + j];
    }
    float c = sigm(gf) * creg[i] + sigm(gi) * tanh_f(gg);
    float h = sigm(go) * tanh_f(c);
    creg[i] = c;
    hh[i] = (_Float16)h;
  }
  astore8(hout + (size_t)(m0 + m) * HHD + hc0 + jb, hh);
  // caller's groupBarrier provides the sync before gbuf is reused
}

__global__ void __launch_bounds__(256, 1)
seq2seq_kernel(const float* x,
               const float* e0wi, const float* e0wh, const float* e0bi, const float* e0bh,
               const float* e1wi, const float* e1wh, const float* e1bi, const float* e1bh,
               const float* d0wi, const float* d0wh, const float* d0bi, const float* d0bh,
               const float* d1wi, const float* d1wh, const float* d1bi, const float* d1bh,
               const float* pw, const float* pb,
               float* out, char* ws) {
  extern __shared__ char smem[];
  int tid = threadIdx.x, bid = blockIdx.x;
  int group = bid >> 6;       // 4 groups x 64 blocks; group owns batch rows [64g, 64g+64)
  int r = bid & 63;
  bool isL1 = (r >= 32);
  int hcTile = r & 31;
  int hc0 = hcTile * 16;
  int m0 = group * 64;
  unsigned* slots = (unsigned*)(ws + WS_BAR) + (size_t)group * 1024;  // 64 slots x 64B
  unsigned barGen = 0;

  _Float16* h0b[2]; _Float16* h1b[2];
  h0b[0] = (_Float16*)(ws + WS_HOFF);
  h0b[1] = (_Float16*)(ws + WS_HOFF + HBYTES);
  h1b[0] = (_Float16*)(ws + WS_HOFF + 2 * HBYTES);
  h1b[1] = (_Float16*)(ws + WS_HOFF + 3 * HBYTES);

  float creg[4];
  creg[0] = 0.f; creg[1] = 0.f; creg[2] = 0.f; creg[3] = 0.f;

  // zero this group's slice of all four h buffers (atomic stores: readers
  // bypass caches, so zeros must be LLC-visible too)
  {
    int q = r >> 4;     // which buffer
    int rb = r & 15;    // 4-row block within group's 64 rows
    char* zp = ws + WS_HOFF + (size_t)q * HBYTES +
               ((size_t)(m0 + rb * 4) * HHD) * 2 + (size_t)tid * 16;
    astore8z(zp);
    astore8z(zp + 8);
  }

  // encoder-role weights + biases into LDS
  if (!isL1) {
    loadWeights(tid, hc0, e0wi, 64, 64, e0wh, 576, SB_ENC0);
    if (tid < 64) {
      int n = (tid >> 4) * HHD + hc0 + (tid & 15);
      ((float*)(smem + BIAS_OFF))[tid] = e0bi[n] + e0bh[n];
    }
  } else {
    loadWeights(tid, hc0, e1wi, 512, 512, e1wh, 1024, SB_ENC1);
    if (tid < 64) {
      int n = (tid >> 4) * HHD + hc0 + (tid & 15);
      ((float*)(smem + BIAS_OFF))[tid] = e1bi[n] + e1bh[n];
    }
  }
  barGen++; groupBarrier(slots, r, barGen);

  // -------- encoder: phase p runs enc0 step p and enc1 step p-1 --------
  for (int p = 0; p <= TINN; ++p) {
    if (!isL1) {
      if (p < TINN)
        gemmStep<9>(tid, m0, hc0, x + (size_t)p * FF, h0b[(p & 1) ^ 1], nullptr,
                    SB_ENC0, 0, h0b[p & 1], creg);
    } else {
      if (p >= 1) {
        int s = p - 1;
        gemmStep<16>(tid, m0, hc0, nullptr, h0b[s & 1], h1b[(s & 1) ^ 1],
                     SB_ENC1, 0, h1b[s & 1], creg);
      }
    }
    barGen++; groupBarrier(slots, r, barGen);
  }

  // -------- switch to decoder-role weights (c state stays in creg) --------
  if (!isL1) {
    loadWeights(tid, hc0, d0wh, 512, 512, nullptr, 512, SB_DEC0);
    if (tid < 64) {
      int n = (tid >> 4) * HHD + hc0 + (tid & 15);
      ((float*)(smem + BIAS_OFF))[tid] = d0bi[n] + d0bh[n];
      ((float*)(smem + WIH0_OFF))[tid] = d0wi[n];
    }
    for (int k = tid; k < 512; k += 256) ((float*)(smem + PROJW_OFF))[k] = pw[k];
    if (tid == 0) ((float*)(smem + PROJB_OFF))[0] = pb[0];
  } else {
    loadWeights(tid, hc0, d1wi, 512, 512, d1wh, 1024, SB_ENC1);
    if (tid < 64) {
      int n = (tid >> 4) * HHD + hc0 + (tid & 15);
      ((float*)(smem + BIAS_OFF))[tid] = d1bi[n] + d1bh[n];
    }
  }
  __syncthreads();
  barGen++; groupBarrier(slots, r, barGen);

  // -------- decoder: 2 phases per step (prev->h0 then h0->h1) --------
  for (int t = 0; t <= TOUTN; ++t) {
    if (!isL1) {
      float* prevl = (float*)(smem + PREV_OFF);
      if (t == 0) {
        if (tid < 64)
          prevl[tid] = x[(size_t)(m0 + tid) * (TINN * FF) + 511 * 64 + 63];
      } else {
        // prev(t) = h1(t-1) . projW + proj_b  (fp32 VALU, 4 threads per row)
        float* part = (float*)(smem + PART_OFF);
        float* pjw = (float*)(smem + PROJW_OFF);
        const _Float16* hrow = h1b[(t - 1) & 1] +
                               (size_t)(m0 + (tid >> 2)) * HHD + (tid & 3) * 128;
        float s = 0.f;
        for (int k8 = 0; k8 < 16; ++k8) {
          v8h hv = aload16(hrow + k8 * 8);
          const float* w = pjw + (tid & 3) * 128 + k8 * 8;
#pragma unroll
          for (int e = 0; e < 8; ++e) s += (float)hv[e] * w[e];
        }
        part[tid] = s;
        __syncthreads();
        if (tid < 64) {
          float p4 = part[tid * 4] + part[tid * 4 + 1] + part[tid * 4 + 2] +
                     part[tid * 4 + 3] + ((float*)(smem + PROJB_OFF))[0];
          prevl[tid] = p4;
          if (hcTile == 0) out[(size_t)(m0 + tid) * TOUTN + (t - 1)] = p4;
        }
      }
      __syncthreads();
      if (t < TOUTN)
        gemmStep<8>(tid, m0, hc0, nullptr, h0b[(t & 1) ^ 1], nullptr,
                    SB_DEC0, 1, h0b[t & 1], creg);
    }
    barGen++; groupBarrier(slots, r, barGen);
    if (isL1 && t < TOUTN)
      gemmStep<16>(tid, m0, hc0, nullptr, h0b[t & 1], h1b[(t & 1) ^ 1],
                   SB_ENC1, 0, h1b[t & 1], creg);
    barGen++; groupBarrier(slots, r, barGen);
  }
}

extern "C" void kernel_launch(void* const* d_in, const int* in_sizes, int n_in,
                              void* d_out, int out_size, void* d_ws, size_t ws_size,
                              hipStream_t stream) {
  const float* x = (const float*)d_in[0];
  // d_in[1] = y (only used for output shape in the reference)
  const float* e0wi = (const float*)d_in[2];
  const float* e0wh = (const float*)d_in[3];
  const float* e0bi = (const float*)d_in[4];
  const float* e0bh = (const float*)d_in[5];
  const float* e1wi = (const float*)d_in[6];
  const float* e1wh = (const float*)d_in[7];
  const float* e1bi = (const float*)d_in[8];
  const float* e1bh = (const float*)d_in[9];
  const float* d0wi = (const float*)d_in[10];
  const float* d0wh = (const float*)d_in[11];
  const float* d0bi = (const float*)d_in[12];
  const float* d0bh = (const float*)d_in[13];
  const float* d1wi = (const float*)d_in[14];
  const float* d1wh = (const float*)d_in[15];
  const float* d1bi = (const float*)d_in[16];
  const float* d1bh = (const float*)d_in[17];
  const float* pw = (const float*)d_in[18];
  const float* pb = (const float*)d_in[19];

  (void)hipFuncSetAttribute((const void*)seq2seq_kernel,
                            hipFuncAttributeMaxDynamicSharedMemorySize, SMEM_TOTAL);
  (void)hipMemsetAsync(d_ws, 0, 16384, stream);  // barrier slots (4 groups x 64)
  seq2seq_kernel<<<dim3(256), dim3(256), SMEM_TOTAL, stream>>>(
      x, e0wi, e0wh, e0bi, e0bh, e1wi, e1wh, e1bi, e1bh,
      d0wi, d0wh, d0bi, d0bh, d1wi, d1wh, d1bi, d1bh,
      pw, pb, (float*)d_out, (char*)d_ws);
}

// Round 6
// 7058.311 us; speedup vs baseline: 4.7103x; 1.5953x over previous
//
#include <hip/hip_runtime.h>

#define TINN 512
#define FF 64
#define HHD 512
#define TOUTN 64

using v8h = __attribute__((ext_vector_type(8))) _Float16;
using v4h = __attribute__((ext_vector_type(4))) _Float16;
using v4f = __attribute__((ext_vector_type(4))) float;
using u32x4 = __attribute__((ext_vector_type(4))) unsigned int;
using u64 = unsigned long long;

#define AGT __HIP_MEMORY_SCOPE_AGENT

// ---------------- LDS layout (bytes) ----------------
// B (weights) stored in MFMA fragment order: element (col c = nt*16+l, k) at
// (((kc*2+ks)*4+nt)*64 + quad*16 + l)*16 + j*2   [k = kc*64+ks*32+quad*8+j]
// -> every ds_read_b128 in the K-loop is base + lane*16: conflict-free.
#define WOFF 0            // max K=1024: 64 cols * 2048 B = 131072
#define GBUF_OFF 131072   // 64 x 65 f32 = 16640
#define BIAS_OFF 147712
#define WIH0_OFF 147968
#define PREV_OFF 148224
#define PART_OFF 148480   // 1024
#define PROJW_OFF 149504  // 2048
#define PROJB_OFF 151552
#define SMEM_TOTAL 151616

// ---------------- workspace layout ----------------
#define WS_BAR 0       // 4 groups x 64 slots x 64B = 16 KB (memset each launch)
#define WS_HOFF 16384  // h0[0], h0[1], h1[0], h1[1] : each 256*512*2 = 262144 B
#define HBYTES (256 * HHD * 2)

static __device__ __forceinline__ float sigm(float x) { return 1.0f / (1.0f + __expf(-x)); }
static __device__ __forceinline__ float tanh_f(float x) { return 1.0f - 2.0f / (1.0f + __expf(2.0f * x)); }

// 8B agent-scope atomics (known-good coherence path: bypass L1/L2, LLC is
// the coherence point; no wbl2/inv fences ever emitted).
static __device__ __forceinline__ v8h aload16(const _Float16* p) {
  union { u64 u[2]; v8h h; } c;
  const u64* q = (const u64*)p;
  c.u[0] = __hip_atomic_load(q, __ATOMIC_RELAXED, AGT);
  c.u[1] = __hip_atomic_load(q + 1, __ATOMIC_RELAXED, AGT);
  return c.h;
}
static __device__ __forceinline__ void astore8(_Float16* p, v4h v) {
  union { u64 u; v4h h; } c;
  c.h = v;
  __hip_atomic_store((u64*)p, c.u, __ATOMIC_RELAXED, AGT);
}
static __device__ __forceinline__ void astore8z(void* p) {
  __hip_atomic_store((u64*)p, 0ull, __ATOMIC_RELAXED, AGT);
}

// 16B L1+L2-bypass loads via buffer intrinsics, aux=17 = sc0|sc1 (GLC|SCC
// in LLVM CPol encoding -> sc0=1, sc1=1 on gfx95x): serviced at the LLC,
// same visibility as the agent atomics but 16B/request and fully
// compiler-pipelined (vmcnt-tracked). Fallback: 2x8B atomic loads.
#if __has_builtin(__builtin_amdgcn_raw_ptr_buffer_load_b128) && \
    __has_builtin(__builtin_amdgcn_make_buffer_rsrc)
#define HAVE_BUFLOAD 1
using rsrc_t = __amdgpu_buffer_rsrc_t;
static __device__ __forceinline__ rsrc_t mkrsrc(const void* p) {
  return __builtin_amdgcn_make_buffer_rsrc((void*)p, (short)0, 0xFFFFFFFFu, 0x00020000);
}
static __device__ __forceinline__ v8h bload16(rsrc_t r, int byteOff) {
  union { u32x4 u; v8h h; } c;
  c.u = __builtin_amdgcn_raw_ptr_buffer_load_b128(r, byteOff, 0, 17);
  return c.h;
}
#else
#define HAVE_BUFLOAD 0
#endif

// Group-local (64-block) slot barrier, contention-free and fence-free.
static __device__ void groupBarrier(unsigned* slots, int r, unsigned target) {
  __builtin_amdgcn_s_waitcnt(0);
  __syncthreads();
  if (threadIdx.x == 0)
    __hip_atomic_store(&slots[(size_t)r * 16], target, __ATOMIC_RELAXED, AGT);
  if (threadIdx.x < 64) {
    while (__hip_atomic_load(&slots[(size_t)threadIdx.x * 16],
                             __ATOMIC_RELAXED, AGT) < target)
      __builtin_amdgcn_s_sleep(1);
  }
  __syncthreads();
#if __has_builtin(__builtin_amdgcn_sched_barrier)
  __builtin_amdgcn_sched_barrier(0);  // keep next phase's loads after the barrier
#endif
}

// Weight slice (64 gate-cols x K) fp32->fp16 into LDS, fragment order.
static __device__ __attribute__((noinline)) void loadWeights(
    int tid, int hc0, const float* W1, int ld1, int K1,
    const float* W2, int K) {
  extern __shared__ char smem[];
  int c = tid >> 2, sub = tid & 3;
  int nt = c >> 4, l = c & 15;
  int n = nt * HHD + hc0 + l;
  int Kq = K >> 2;
  for (int k = sub * Kq; k < (sub + 1) * Kq; ++k) {
    float v;
    if (k < K1) v = W1[(size_t)n * ld1 + k];
    else        v = W2[(size_t)n * HHD + (k - K1)];
    int kc = k >> 6, ks = (k >> 5) & 1, quad = (k >> 3) & 3, j = k & 7;
    int off = (((kc * 2 + ks) * 4 + nt) * 64 + quad * 16 + l) * 16 + j * 2;
    *(_Float16*)(smem + WOFF + off) = (_Float16)v;
  }
}

// One LSTM cell step for this block's (m0 batch rows, hc0 h-cols) 64x16 tile.
// Waves partition M (wave w = rows w*16..w*16+15): A read exactly once per
// block, direct global->reg (16B bypass loads); B from LDS conflict-free.
template <int NC>
static __device__ __attribute__((noinline)) void gemmStep(
    int tid, int m0, int hc0, const float* xstep,
    const _Float16* src1, const _Float16* src2,
    int rank1, _Float16* hout, float* creg) {
  extern __shared__ char smem[];
  int lane = tid & 63, wave = tid >> 6;
  int l15 = lane & 15, quad = lane >> 4;

  v4f zero4 = {0.f, 0.f, 0.f, 0.f};
  v4f acc0 = zero4, acc1 = zero4, acc2 = zero4, acc3 = zero4;

  int ra = m0 + wave * 16 + l15;           // this lane's A row
  int rowOff = ra * HHD * 2;               // byte offset of row in h buffer
#if HAVE_BUFLOAD
  rsrc_t r1 = mkrsrc(src1);
  rsrc_t r2 = (src2 != nullptr) ? mkrsrc(src2) : r1;
#endif
  const char* wb = smem + WOFF + (size_t)lane * 16;

#pragma unroll
  for (int ci = 0; ci < NC; ++ci) {
    v8h ak0, ak1;
    if (xstep != nullptr && ci == 0) {
      // chunk 0 of encoder layer0: fp32 x cols 0..63 (normal cached loads;
      // x is never written -> no staleness hazard)
      const float* xr = xstep + (size_t)ra * (TINN * FF) + quad * 8;
      v4f f00 = *(const v4f*)(xr);
      v4f f01 = *(const v4f*)(xr + 4);
      v4f f10 = *(const v4f*)(xr + 32);
      v4f f11 = *(const v4f*)(xr + 36);
#pragma unroll
      for (int e = 0; e < 4; ++e) {
        ak0[e] = (_Float16)f00[e]; ak0[4 + e] = (_Float16)f01[e];
        ak1[e] = (_Float16)f10[e]; ak1[4 + e] = (_Float16)f11[e];
      }
    } else {
      int cj = (xstep != nullptr) ? ci - 1 : ci;
      bool inS2 = (src2 != nullptr) && (cj >= 8);
      int colOff = ((inS2 ? cj - 8 : cj) * 64 + quad * 8) * 2;
#if HAVE_BUFLOAD
      ak0 = bload16(inS2 ? r2 : r1, rowOff + colOff);
      ak1 = bload16(inS2 ? r2 : r1, rowOff + colOff + 64);
#else
      const _Float16* pr = (inS2 ? src2 : src1) + (size_t)ra * HHD +
                           (inS2 ? cj - 8 : cj) * 64 + quad * 8;
      ak0 = aload16(pr);
      ak1 = aload16(pr + 32);
#endif
    }
    const char* bb = wb + (size_t)ci * 8192;
#pragma unroll
    for (int ks = 0; ks < 2; ++ks) {
      v8h a = ks ? ak1 : ak0;
      v8h b0 = *(const v8h*)(bb + (ks * 4 + 0) * 1024);
      v8h b1 = *(const v8h*)(bb + (ks * 4 + 1) * 1024);
      v8h b2 = *(const v8h*)(bb + (ks * 4 + 2) * 1024);
      v8h b3 = *(const v8h*)(bb + (ks * 4 + 3) * 1024);
      acc0 = __builtin_amdgcn_mfma_f32_16x16x32_f16(a, b0, acc0, 0, 0, 0);
      acc1 = __builtin_amdgcn_mfma_f32_16x16x32_f16(a, b1, acc1, 0, 0, 0);
      acc2 = __builtin_amdgcn_mfma_f32_16x16x32_f16(a, b2, acc2, 0, 0, 0);
      acc3 = __builtin_amdgcn_mfma_f32_16x16x32_f16(a, b3, acc3, 0, 0, 0);
    }
  }

  // gates -> LDS gbuf (free since prior phase's reads completed pre-barrier)
  float* gb = (float*)(smem + GBUF_OFF);
#pragma unroll
  for (int r = 0; r < 4; ++r) {
    int row = wave * 16 + quad * 4 + r;
    gb[row * 65 + l15] = acc0[r];
    gb[row * 65 + 16 + l15] = acc1[r];
    gb[row * 65 + 32 + l15] = acc2[r];
    gb[row * 65 + 48 + l15] = acc3[r];
  }
  __syncthreads();

  float* bias = (float*)(smem + BIAS_OFF);
  float* wih0 = (float*)(smem + WIH0_OFF);
  float* prevl = (float*)(smem + PREV_OFF);
  int m = tid >> 2, jb = (tid & 3) * 4;
  float pv = rank1 ? prevl[m] : 0.0f;
  v4h hh;
#pragma unroll
  for (int i = 0; i < 4; ++i) {
    int j = jb + i;
    float gi = gb[m * 65 + j] + bias[j];
    float gf = gb[m * 65 + 16 + j] + bias[16 + j];
    float gg = gb[m * 65 + 32 + j] + bias[32 + j];
    float go = gb[m * 65 + 48 + j] + bias[48 + j];
    if (rank1) {
      gi += pv * wih0[j]; gf += pv * wih0[16 + j];
      gg += pv * wih0[32 + j]; go += pv * wih0[48 + j];
    }
    float c = sigm(gf) * creg[i] + sigm(gi) * tanh_f(gg);
    float h = sigm(go) * tanh_f(c);
    creg[i] = c;
    hh[i] = (_Float16)h;
  }
  astore8(hout + (size_t)(m0 + m) * HHD + hc0 + jb, hh);
  // caller's groupBarrier provides the sync before gbuf is reused
}

__global__ void __launch_bounds__(256, 1)
seq2seq_kernel(const float* x,
               const float* e0wi, const float* e0wh, const float* e0bi, const float* e0bh,
               const float* e1wi, const float* e1wh, const float* e1bi, const float* e1bh,
               const float* d0wi, const float* d0wh, const float* d0bi, const float* d0bh,
               const float* d1wi, const float* d1wh, const float* d1bi, const float* d1bh,
               const float* pw, const float* pb,
               float* out, char* ws) {
  extern __shared__ char smem[];
  int tid = threadIdx.x, bid = blockIdx.x;
  int group = bid >> 6;       // 4 groups x 64 blocks; group owns batch rows [64g, 64g+64)
  int r = bid & 63;
  bool isL1 = (r >= 32);
  int hcTile = r & 31;
  int hc0 = hcTile * 16;
  int m0 = group * 64;
  unsigned* slots = (unsigned*)(ws + WS_BAR) + (size_t)group * 1024;  // 64 slots x 64B
  unsigned barGen = 0;

  _Float16* h0b[2]; _Float16* h1b[2];
  h0b[0] = (_Float16*)(ws + WS_HOFF);
  h0b[1] = (_Float16*)(ws + WS_HOFF + HBYTES);
  h1b[0] = (_Float16*)(ws + WS_HOFF + 2 * HBYTES);
  h1b[1] = (_Float16*)(ws + WS_HOFF + 3 * HBYTES);

  float creg[4];
  creg[0] = 0.f; creg[1] = 0.f; creg[2] = 0.f; creg[3] = 0.f;

  // zero this group's slice of all four h buffers (LLC-visible stores)
  {
    int q = r >> 4;     // which buffer
    int rb = r & 15;    // 4-row block within group's 64 rows
    char* zp = ws + WS_HOFF + (size_t)q * HBYTES +
               ((size_t)(m0 + rb * 4) * HHD) * 2 + (size_t)tid * 16;
    astore8z(zp);
    astore8z(zp + 8);
  }

  // encoder-role weights + biases into LDS
  if (!isL1) {
    loadWeights(tid, hc0, e0wi, 64, 64, e0wh, 576);
    if (tid < 64) {
      int n = (tid >> 4) * HHD + hc0 + (tid & 15);
      ((float*)(smem + BIAS_OFF))[tid] = e0bi[n] + e0bh[n];
    }
  } else {
    loadWeights(tid, hc0, e1wi, 512, 512, e1wh, 1024);
    if (tid < 64) {
      int n = (tid >> 4) * HHD + hc0 + (tid & 15);
      ((float*)(smem + BIAS_OFF))[tid] = e1bi[n] + e1bh[n];
    }
  }
  barGen++; groupBarrier(slots, r, barGen);

  // -------- encoder: phase p runs enc0 step p and enc1 step p-1 --------
  for (int p = 0; p <= TINN; ++p) {
    if (!isL1) {
      if (p < TINN)
        gemmStep<9>(tid, m0, hc0, x + (size_t)p * FF, h0b[(p & 1) ^ 1], nullptr,
                    0, h0b[p & 1], creg);
    } else {
      if (p >= 1) {
        int s = p - 1;
        gemmStep<16>(tid, m0, hc0, nullptr, h0b[s & 1], h1b[(s & 1) ^ 1],
                     0, h1b[s & 1], creg);
      }
    }
    barGen++; groupBarrier(slots, r, barGen);
  }

  // -------- switch to decoder-role weights (c state stays in creg) --------
  if (!isL1) {
    loadWeights(tid, hc0, d0wh, 512, 512, nullptr, 512);
    if (tid < 64) {
      int n = (tid >> 4) * HHD + hc0 + (tid & 15);
      ((float*)(smem + BIAS_OFF))[tid] = d0bi[n] + d0bh[n];
      ((float*)(smem + WIH0_OFF))[tid] = d0wi[n];
    }
    for (int k = tid; k < 512; k += 256) ((float*)(smem + PROJW_OFF))[k] = pw[k];
    if (tid == 0) ((float*)(smem + PROJB_OFF))[0] = pb[0];
  } else {
    loadWeights(tid, hc0, d1wi, 512, 512, d1wh, 1024);
    if (tid < 64) {
      int n = (tid >> 4) * HHD + hc0 + (tid & 15);
      ((float*)(smem + BIAS_OFF))[tid] = d1bi[n] + d1bh[n];
    }
  }
  __syncthreads();
  barGen++; groupBarrier(slots, r, barGen);

  // -------- decoder: 2 phases per step (prev->h0 then h0->h1) --------
  for (int t = 0; t <= TOUTN; ++t) {
    if (!isL1) {
      float* prevl = (float*)(smem + PREV_OFF);
      if (t == 0) {
        if (tid < 64)
          prevl[tid] = x[(size_t)(m0 + tid) * (TINN * FF) + 511 * 64 + 63];
      } else {
        // prev(t) = h1(t-1) . projW + proj_b  (fp32 VALU, 4 threads per row)
        float* part = (float*)(smem + PART_OFF);
        float* pjw = (float*)(smem + PROJW_OFF);
        const _Float16* hrow = h1b[(t - 1) & 1] +
                               (size_t)(m0 + (tid >> 2)) * HHD + (tid & 3) * 128;
        float s = 0.f;
        for (int k8 = 0; k8 < 16; ++k8) {
          v8h hv = aload16(hrow + k8 * 8);
          const float* w = pjw + (tid & 3) * 128 + k8 * 8;
#pragma unroll
          for (int e = 0; e < 8; ++e) s += (float)hv[e] * w[e];
        }
        part[tid] = s;
        __syncthreads();
        if (tid < 64) {
          float p4 = part[tid * 4] + part[tid * 4 + 1] + part[tid * 4 + 2] +
                     part[tid * 4 + 3] + ((float*)(smem + PROJB_OFF))[0];
          prevl[tid] = p4;
          if (hcTile == 0) out[(size_t)(m0 + tid) * TOUTN + (t - 1)] = p4;
        }
      }
      __syncthreads();
      if (t < TOUTN)
        gemmStep<8>(tid, m0, hc0, nullptr, h0b[(t & 1) ^ 1], nullptr,
                    1, h0b[t & 1], creg);
    }
    barGen++; groupBarrier(slots, r, barGen);
    if (isL1 && t < TOUTN)
      gemmStep<16>(tid, m0, hc0, nullptr, h0b[t & 1], h1b[(t & 1) ^ 1],
                   0, h1b[t & 1], creg);
    barGen++; groupBarrier(slots, r, barGen);
  }
}

extern "C" void kernel_launch(void* const* d_in, const int* in_sizes, int n_in,
                              void* d_out, int out_size, void* d_ws, size_t ws_size,
                              hipStream_t stream) {
  const float* x = (const float*)d_in[0];
  const float* e0wi = (const float*)d_in[2];
  const float* e0wh = (const float*)d_in[3];
  const float* e0bi = (const float*)d_in[4];
  const float* e0bh = (const float*)d_in[5];
  const float* e1wi = (const float*)d_in[6];
  const float* e1wh = (const float*)d_in[7];
  const float* e1bi = (const float*)d_in[8];
  const float* e1bh = (const float*)d_in[9];
  const float* d0wi = (const float*)d_in[10];
  const float* d0wh = (const float*)d_in[11];
  const float* d0bi = (const float*)d_in[12];
  const float* d0bh = (const float*)d_in[13];
  const float* d1wi = (const float*)d_in[14];
  const float* d1wh = (const float*)d_in[15];
  const float* d1bi = (const float*)d_in[16];
  const float* d1bh = (const float*)d_in[17];
  const float* pw = (const float*)d_in[18];
  const float* pb = (const float*)d_in[19];

  (void)hipFuncSetAttribute((const void*)seq2seq_kernel,
                            hipFuncAttributeMaxDynamicSharedMemorySize, SMEM_TOTAL);
  (void)hipMemsetAsync(d_ws, 0, 16384, stream);  // barrier slots (4 groups x 64)
  seq2seq_kernel<<<dim3(256), dim3(256), SMEM_TOTAL, stream>>>(
      x, e0wi, e0wh, e0bi, e0bh, e1wi, e1wh, e1bi, e1bh,
      d0wi, d0wh, d0bi, d0bh, d1wi, d1wh, d1bi, d1bh,
      pw, pb, (float*)d_out, (char*)d_ws);
}